// Round 1
// baseline (666.626 us; speedup 1.0000x reference)
//
#include <hip/hip_runtime.h>

#define S_LEN 2048
#define HID   2048
#define NHEAD 16
#define HD    128
#define BSZ   2
#define BS_TOT (BSZ * S_LEN)   // 4096

typedef __bf16 bf16x8 __attribute__((ext_vector_type(8)));
typedef unsigned short u16x8 __attribute__((ext_vector_type(8)));
typedef float f32x4 __attribute__((ext_vector_type(4)));

static __device__ __forceinline__ bf16x8 as_bf(u16x8 v) { return __builtin_bit_cast(bf16x8, v); }

static __device__ __forceinline__ unsigned short f2bf(float f) {
  unsigned int u = __builtin_bit_cast(unsigned int, f);
  u += 0x7fffu + ((u >> 16) & 1u);   // RNE
  return (unsigned short)(u >> 16);
}
static __device__ __forceinline__ float bf2f(unsigned short b) {
  unsigned int u = ((unsigned int)b) << 16;
  return __builtin_bit_cast(float, u);
}

// ---------------- fp32 -> bf16 convert (vectorized) ----------------
__global__ __launch_bounds__(256) void cvt_bf16(const float* __restrict__ in,
                                                unsigned short* __restrict__ out) {
  int i = blockIdx.x * 256 + threadIdx.x;
  float4 v = ((const float4*)in)[i];
  ushort4 o;
  o.x = f2bf(v.x); o.y = f2bf(v.y); o.z = f2bf(v.z); o.w = f2bf(v.w);
  ((ushort4*)out)[i] = o;
}

// ---------------- RoPE cos/sin table: [S][64] ----------------
__global__ __launch_bounds__(256) void rope_table(float* __restrict__ ct, float* __restrict__ st) {
  int id = blockIdx.x * 256 + threadIdx.x;   // S*64 threads
  int t = id >> 6, d = id & 63;
  float inv = powf(10000.0f, -(float)d * (1.0f / 64.0f));
  float f = (float)t * inv;
  float sv, cv;
  sincosf(f, &sv, &cv);
  ct[id] = cv; st[id] = sv;
}

// ---------------- RoPE apply in-place on q,k (layout [m][H]) ----------------
__global__ __launch_bounds__(256) void rope_apply(unsigned short* __restrict__ q,
                                                  unsigned short* __restrict__ k,
                                                  const float* __restrict__ ct,
                                                  const float* __restrict__ st) {
  int id = blockIdx.x * 256 + threadIdx.x;   // BS_TOT*NHEAD*64 threads
  int d = id & 63;
  int h = (id >> 6) & (NHEAD - 1);
  int m = id >> 10;
  int s = m & (S_LEN - 1);
  float c = ct[s * 64 + d], sn = st[s * 64 + d];
  size_t base = (size_t)m * HID + h * HD + d;
  float q1 = bf2f(q[base]), q2 = bf2f(q[base + 64]);
  q[base]      = f2bf(q1 * c - q2 * sn);
  q[base + 64] = f2bf(q2 * c + q1 * sn);
  float k1 = bf2f(k[base]), k2 = bf2f(k[base + 64]);
  k[base]      = f2bf(k1 * c - k2 * sn);
  k[base + 64] = f2bf(k2 * c + k1 * sn);
}

// ---------------- GEMM: C[m][n] = sum_k A[m][k] * Bw[n][k]  (B^T pattern) ----------------
// 128x128 tile, BK=32, 4 waves (2x2), each wave 64x64 via 4x4 16x16x32 MFMA frags.
template <typename OutT>
__global__ __launch_bounds__(256) void gemm_bt(const unsigned short* __restrict__ A,
                                               const unsigned short* __restrict__ Bw,
                                               OutT* __restrict__ C, int M, int N, int K) {
  __shared__ __align__(16) unsigned short As[128 * 32];
  __shared__ __align__(16) unsigned short Bs[128 * 32];
  const int nbn = N >> 7;
  int bm = blockIdx.x / nbn, bn = blockIdx.x % nbn;
  int tid = (int)threadIdx.x;
  int l = tid & 63, lr = l & 15, lg = l >> 4;
  int w = tid >> 6, wm = w >> 1, wn = w & 1;

  // staging: pass0 row = tid>>2, pass1 row = +64; c8 = tid&3 (8-elem k-block)
  int rA0 = tid >> 2, c8 = tid & 3;
  size_t gA0 = (size_t)(bm * 128 + rA0) * K + c8 * 8;
  size_t gB0 = (size_t)(bn * 128 + rA0) * K + c8 * 8;
  int ws0 = rA0 * 32 + ((c8 ^ (rA0 & 3)) << 3);   // XOR swizzle on k-block
  int ws1 = ws0 + 64 * 32;                        // (rA0+64)&3 == rA0&3

  // frag LDS read offsets
  int aoff[4], boff[4];
#pragma unroll
  for (int i = 0; i < 4; ++i) {
    int rowa = wm * 64 + i * 16 + lr;
    aoff[i] = rowa * 32 + ((lg ^ (rowa & 3)) << 3);
    int rowb = wn * 64 + i * 16 + lr;
    boff[i] = rowb * 32 + ((lg ^ (rowb & 3)) << 3);
  }

  f32x4 zero = {0.f, 0.f, 0.f, 0.f};
  f32x4 acc[4][4];
#pragma unroll
  for (int mi = 0; mi < 4; ++mi)
#pragma unroll
    for (int ni = 0; ni < 4; ++ni) acc[mi][ni] = zero;

  int nk = K >> 5;
  u16x8 ra0 = *(const u16x8*)(A + gA0);
  u16x8 ra1 = *(const u16x8*)(A + gA0 + (size_t)64 * K);
  u16x8 rb0 = *(const u16x8*)(Bw + gB0);
  u16x8 rb1 = *(const u16x8*)(Bw + gB0 + (size_t)64 * K);

  for (int kt = 0; kt < nk; ++kt) {
    __syncthreads();
    *(u16x8*)&As[ws0] = ra0; *(u16x8*)&As[ws1] = ra1;
    *(u16x8*)&Bs[ws0] = rb0; *(u16x8*)&Bs[ws1] = rb1;
    __syncthreads();
    if (kt + 1 < nk) {
      size_t kadd = (size_t)(kt + 1) * 32;
      ra0 = *(const u16x8*)(A + gA0 + kadd);
      ra1 = *(const u16x8*)(A + gA0 + (size_t)64 * K + kadd);
      rb0 = *(const u16x8*)(Bw + gB0 + kadd);
      rb1 = *(const u16x8*)(Bw + gB0 + (size_t)64 * K + kadd);
    }
    u16x8 af[4], bfr[4];
#pragma unroll
    for (int i = 0; i < 4; ++i) {
      af[i]  = *(const u16x8*)&As[aoff[i]];
      bfr[i] = *(const u16x8*)&Bs[boff[i]];
    }
#pragma unroll
    for (int mi = 0; mi < 4; ++mi)
#pragma unroll
      for (int ni = 0; ni < 4; ++ni)
        acc[mi][ni] = __builtin_amdgcn_mfma_f32_16x16x32_bf16(as_bf(af[mi]), as_bf(bfr[ni]),
                                                              acc[mi][ni], 0, 0, 0);
  }

  // epilogue: C row = 4*lg + j, col = lr (within 16x16 frag)
#pragma unroll
  for (int mi = 0; mi < 4; ++mi) {
#pragma unroll
    for (int ni = 0; ni < 4; ++ni) {
      int col = bn * 128 + wn * 64 + ni * 16 + lr;
#pragma unroll
      for (int j = 0; j < 4; ++j) {
        int rowm = bm * 128 + wm * 64 + mi * 16 + 4 * lg + j;
        float v = acc[mi][ni][j];
        if constexpr (sizeof(OutT) == 2) C[(size_t)rowm * N + col] = f2bf(v);
        else                             C[(size_t)rowm * N + col] = v;
      }
    }
  }
}

// ---------------- Flash attention (causal), q/k/v layout [m][H], per-head slice ----------------
// Block: 4 waves, 64 q-rows; wave w owns q rows [w*16, w*16+16).
// K b-frags read straight from global (L1/L2). V staged transposed+swizzled in LDS.
__global__ __launch_bounds__(256) void attn_fwd(const unsigned short* __restrict__ qg,
                                                const unsigned short* __restrict__ kg,
                                                const unsigned short* __restrict__ vg,
                                                unsigned short* __restrict__ ctx) {
  __shared__ __align__(16) unsigned short VT[128 * 72];      // [d][k'] k' = k ^ (((d>>3)&7)<<3)
  __shared__ __align__(16) unsigned short Pl[4 * 16 * 72];   // per-wave P (16 q x 64 kv), pad 72
  int q0 = blockIdx.x * 64;
  int bh = blockIdx.y;
  int b = bh >> 4, h = bh & 15;
  int tid = (int)threadIdx.x, w = tid >> 6, l = tid & 63, lr = l & 15, lg = l >> 4;
  const float scale = 0.08838834764831845f;  // 1/sqrt(128)

  // Q fragments (RoPE already applied)
  const unsigned short* qbase = qg + (size_t)(b * S_LEN + q0 + w * 16 + lr) * HID + h * HD;
  u16x8 qf[4];
#pragma unroll
  for (int kk = 0; kk < 4; ++kk) qf[kk] = *(const u16x8*)(qbase + kk * 32 + lg * 8);

  f32x4 zero = {0.f, 0.f, 0.f, 0.f};
  f32x4 oacc[8];
#pragma unroll
  for (int i = 0; i < 8; ++i) oacc[i] = zero;
  float mrow[4], lsum[4];
#pragma unroll
  for (int j = 0; j < 4; ++j) { mrow[j] = -1e30f; lsum[j] = 0.f; }

  int sc8 = tid & 15;   // d-block for V staging
  int sr0 = tid >> 4;   // kv row base
  int nkv = (q0 >> 6) + 1;

  for (int t = 0; t < nkv; ++t) {
    int k0 = t * 64;
    __syncthreads();   // previous tile's VT reads done
    // ---- stage V transposed: VT[d][k ^ f(d)] ----
#pragma unroll
    for (int it = 0; it < 4; ++it) {
      int r = it * 16 + sr0;
      u16x8 vv = *(const u16x8*)(vg + (size_t)(b * S_LEN + k0 + r) * HID + h * HD + sc8 * 8);
      int kp = r ^ ((sc8 & 7) << 3);
#pragma unroll
      for (int j = 0; j < 8; ++j) VT[(sc8 * 8 + j) * 72 + kp] = vv[j];
    }
    __syncthreads();

    // ---- S = Q K^T (K frags from global) ----
    f32x4 sacc[4];
#pragma unroll
    for (int ni = 0; ni < 4; ++ni) sacc[ni] = zero;
    const unsigned short* kb0 = kg + (size_t)(b * S_LEN + k0 + lr) * HID + h * HD + lg * 8;
#pragma unroll
    for (int kk = 0; kk < 4; ++kk) {
#pragma unroll
      for (int ni = 0; ni < 4; ++ni) {
        u16x8 kf = *(const u16x8*)(kb0 + (size_t)ni * 16 * HID + kk * 32);
        sacc[ni] = __builtin_amdgcn_mfma_f32_16x16x32_bf16(as_bf(qf[kk]), as_bf(kf), sacc[ni], 0, 0, 0);
      }
    }

    // ---- online softmax (rows live in 16-lane groups; row = 4*lg + j) ----
    float sv[4][4];
#pragma unroll
    for (int ni = 0; ni < 4; ++ni)
#pragma unroll
      for (int j = 0; j < 4; ++j) sv[ni][j] = sacc[ni][j] * scale;
    if (t == nkv - 1) {  // diagonal tile (k0 == q0): mask kc > qr
#pragma unroll
      for (int ni = 0; ni < 4; ++ni)
#pragma unroll
        for (int j = 0; j < 4; ++j)
          if (ni * 16 + lr > w * 16 + 4 * lg + j) sv[ni][j] = -1e30f;
    }
    float mx[4], alpha[4], rs[4];
#pragma unroll
    for (int j = 0; j < 4; ++j) {
      mx[j] = fmaxf(fmaxf(sv[0][j], sv[1][j]), fmaxf(sv[2][j], sv[3][j]));
      mx[j] = fmaxf(mx[j], __shfl_xor(mx[j], 1, 64));
      mx[j] = fmaxf(mx[j], __shfl_xor(mx[j], 2, 64));
      mx[j] = fmaxf(mx[j], __shfl_xor(mx[j], 4, 64));
      mx[j] = fmaxf(mx[j], __shfl_xor(mx[j], 8, 64));
      float mn = fmaxf(mrow[j], mx[j]);
      alpha[j] = __expf(mrow[j] - mn);
      mrow[j] = mn;
      rs[j] = 0.f;
    }
    float pv[4][4];
#pragma unroll
    for (int ni = 0; ni < 4; ++ni)
#pragma unroll
      for (int j = 0; j < 4; ++j) { pv[ni][j] = __expf(sv[ni][j] - mrow[j]); rs[j] += pv[ni][j]; }
#pragma unroll
    for (int j = 0; j < 4; ++j) {
      rs[j] += __shfl_xor(rs[j], 1, 64);
      rs[j] += __shfl_xor(rs[j], 2, 64);
      rs[j] += __shfl_xor(rs[j], 4, 64);
      rs[j] += __shfl_xor(rs[j], 8, 64);
      lsum[j] = lsum[j] * alpha[j] + rs[j];
    }
#pragma unroll
    for (int nj = 0; nj < 8; ++nj) {
      oacc[nj][0] *= alpha[0]; oacc[nj][1] *= alpha[1];
      oacc[nj][2] *= alpha[2]; oacc[nj][3] *= alpha[3];
    }

    // ---- P -> per-wave LDS (transpose to A-frag layout) ----
    unsigned short* pw = &Pl[w * 16 * 72];
#pragma unroll
    for (int ni = 0; ni < 4; ++ni)
#pragma unroll
      for (int j = 0; j < 4; ++j)
        pw[(4 * lg + j) * 72 + ni * 16 + lr] = f2bf(pv[ni][j]);

    // ---- O += P V ----
#pragma unroll
    for (int kk2 = 0; kk2 < 2; ++kk2) {
      u16x8 pf = *(const u16x8*)&pw[lr * 72 + kk2 * 32 + lg * 8];
#pragma unroll
      for (int nj = 0; nj < 8; ++nj) {
        int d = nj * 16 + lr;
        int fx = ((d >> 3) & 7) << 3;
        u16x8 vf = *(const u16x8*)&VT[d * 72 + ((kk2 * 32 + lg * 8) ^ fx)];
        oacc[nj] = __builtin_amdgcn_mfma_f32_16x16x32_bf16(as_bf(pf), as_bf(vf), oacc[nj], 0, 0, 0);
      }
    }
  }

  // ---- epilogue: ctx[m][h*128 + d] = O / lsum ----
  float rinv[4];
#pragma unroll
  for (int j = 0; j < 4; ++j) rinv[j] = 1.0f / lsum[j];
  size_t obase = (size_t)(b * S_LEN + q0 + w * 16 + 4 * lg) * HID + h * HD;
#pragma unroll
  for (int nj = 0; nj < 8; ++nj)
#pragma unroll
    for (int j = 0; j < 4; ++j)
      ctx[obase + (size_t)j * HID + nj * 16 + lr] = f2bf(oacc[nj][j] * rinv[j]);
}

// ---------------- launch ----------------
extern "C" void kernel_launch(void* const* d_in, const int* in_sizes, int n_in,
                              void* d_out, int out_size, void* d_ws, size_t ws_size,
                              hipStream_t stream) {
  const float* hs = (const float*)d_in[0];
  const float* Wq = (const float*)d_in[1];
  const float* Wk = (const float*)d_in[2];
  const float* Wv = (const float*)d_in[3];
  const float* Wo = (const float*)d_in[4];

  char* ws = (char*)d_ws;
  // workspace layout (~97 MB)
  unsigned short* hsb = (unsigned short*)(ws);                    // 16 MB (reused as ctx)
  unsigned short* wqb = (unsigned short*)(ws + 16777216);         // 8 MB
  unsigned short* wkb = (unsigned short*)(ws + 25165824);
  unsigned short* wvb = (unsigned short*)(ws + 33554432);
  unsigned short* wob = (unsigned short*)(ws + 41943040);
  unsigned short* qb  = (unsigned short*)(ws + 50331648);         // 16 MB
  unsigned short* kb  = (unsigned short*)(ws + 67108864);
  unsigned short* vb  = (unsigned short*)(ws + 83886080);
  float* ctab = (float*)(ws + 100663296);                         // S*64 f32
  float* stab = (float*)(ws + 101187584);
  unsigned short* ctxb = hsb;  // overlay: hsb fully consumed before attn writes

  // converts
  cvt_bf16<<<8192, 256, 0, stream>>>(hs, hsb);   // BS_TOT*HID / 1024
  cvt_bf16<<<4096, 256, 0, stream>>>(Wq, wqb);   // HID*HID / 1024
  cvt_bf16<<<4096, 256, 0, stream>>>(Wk, wkb);
  cvt_bf16<<<4096, 256, 0, stream>>>(Wv, wvb);
  cvt_bf16<<<4096, 256, 0, stream>>>(Wo, wob);
  rope_table<<<512, 256, 0, stream>>>(ctab, stab);

  // QKV projections: [4096 x 2048] = hsb @ W^T
  gemm_bt<unsigned short><<<512, 256, 0, stream>>>(hsb, wqb, qb, BS_TOT, HID, HID);
  gemm_bt<unsigned short><<<512, 256, 0, stream>>>(hsb, wkb, kb, BS_TOT, HID, HID);
  gemm_bt<unsigned short><<<512, 256, 0, stream>>>(hsb, wvb, vb, BS_TOT, HID, HID);

  rope_apply<<<16384, 256, 0, stream>>>(qb, kb, ctab, stab);

  attn_fwd<<<dim3(S_LEN / 64, BSZ * NHEAD), 256, 0, stream>>>(qb, kb, vb, ctxb);

  // output projection -> fp32 d_out
  gemm_bt<float><<<512, 256, 0, stream>>>(ctxb, wob, (float*)d_out, BS_TOT, HID, HID);

  (void)in_sizes; (void)n_in; (void)out_size; (void)ws_size;
}

// Round 2
// 298.940 us; speedup vs baseline: 2.2300x; 2.2300x over previous
//
#include <hip/hip_runtime.h>

#define S_LEN 2048
#define HID   2048
#define NHEAD 16
#define HD    128
#define BSZ   2
#define BS_TOT (BSZ * S_LEN)   // 4096

typedef __bf16 bf16x8 __attribute__((ext_vector_type(8)));
typedef unsigned short u16x8 __attribute__((ext_vector_type(8)));
typedef unsigned short u16x4 __attribute__((ext_vector_type(4)));
typedef float f32x4 __attribute__((ext_vector_type(4)));

static __device__ __forceinline__ bf16x8 as_bf(u16x8 v) { return __builtin_bit_cast(bf16x8, v); }

static __device__ __forceinline__ unsigned short f2bf(float f) {
  unsigned int u = __builtin_bit_cast(unsigned int, f);
  u += 0x7fffu + ((u >> 16) & 1u);   // RNE
  return (unsigned short)(u >> 16);
}
static __device__ __forceinline__ float bf2f(unsigned short b) {
  unsigned int u = ((unsigned int)b) << 16;
  return __builtin_bit_cast(float, u);
}

// ---------------- fp32 -> bf16 convert (vectorized) ----------------
__global__ __launch_bounds__(256) void cvt_bf16(const float* __restrict__ in,
                                                unsigned short* __restrict__ out) {
  int i = blockIdx.x * 256 + threadIdx.x;
  float4 v = ((const float4*)in)[i];
  ushort4 o;
  o.x = f2bf(v.x); o.y = f2bf(v.y); o.z = f2bf(v.z); o.w = f2bf(v.w);
  ((ushort4*)out)[i] = o;
}

// ---------------- RoPE cos/sin table: [S][64] ----------------
__global__ __launch_bounds__(256) void rope_table(float* __restrict__ ct, float* __restrict__ st) {
  int id = blockIdx.x * 256 + threadIdx.x;   // S*64 threads
  int t = id >> 6, d = id & 63;
  float inv = powf(10000.0f, -(float)d * (1.0f / 64.0f));
  float f = (float)t * inv;
  float sv, cv;
  sincosf(f, &sv, &cv);
  ct[id] = cv; st[id] = sv;
}

// ---------------- RoPE apply in-place on q,k (layout [m][H]) ----------------
__global__ __launch_bounds__(256) void rope_apply(unsigned short* __restrict__ q,
                                                  unsigned short* __restrict__ k,
                                                  const float* __restrict__ ct,
                                                  const float* __restrict__ st) {
  int id = blockIdx.x * 256 + threadIdx.x;   // BS_TOT*NHEAD*64 threads
  int d = id & 63;
  int h = (id >> 6) & (NHEAD - 1);
  int m = id >> 10;
  int s = m & (S_LEN - 1);
  float c = ct[s * 64 + d], sn = st[s * 64 + d];
  size_t base = (size_t)m * HID + h * HD + d;
  float q1 = bf2f(q[base]), q2 = bf2f(q[base + 64]);
  q[base]      = f2bf(q1 * c - q2 * sn);
  q[base + 64] = f2bf(q2 * c + q1 * sn);
  float k1 = bf2f(k[base]), k2 = bf2f(k[base + 64]);
  k[base]      = f2bf(k1 * c - k2 * sn);
  k[base + 64] = f2bf(k2 * c + k1 * sn);
}

// ---------------- GEMM: C[m][n] = sum_k A[m][k] * Bw[n][k]  (B^T pattern) ----------------
template <typename OutT>
__global__ __launch_bounds__(256) void gemm_bt(const unsigned short* __restrict__ A,
                                               const unsigned short* __restrict__ Bw,
                                               OutT* __restrict__ C, int M, int N, int K) {
  __shared__ __align__(16) unsigned short As[128 * 32];
  __shared__ __align__(16) unsigned short Bs[128 * 32];
  const int nbn = N >> 7;
  int bm = blockIdx.x / nbn, bn = blockIdx.x % nbn;
  int tid = (int)threadIdx.x;
  int l = tid & 63, lr = l & 15, lg = l >> 4;
  int w = tid >> 6, wm = w >> 1, wn = w & 1;

  int rA0 = tid >> 2, c8 = tid & 3;
  size_t gA0 = (size_t)(bm * 128 + rA0) * K + c8 * 8;
  size_t gB0 = (size_t)(bn * 128 + rA0) * K + c8 * 8;
  int ws0 = rA0 * 32 + ((c8 ^ (rA0 & 3)) << 3);
  int ws1 = ws0 + 64 * 32;

  int aoff[4], boff[4];
#pragma unroll
  for (int i = 0; i < 4; ++i) {
    int rowa = wm * 64 + i * 16 + lr;
    aoff[i] = rowa * 32 + ((lg ^ (rowa & 3)) << 3);
    int rowb = wn * 64 + i * 16 + lr;
    boff[i] = rowb * 32 + ((lg ^ (rowb & 3)) << 3);
  }

  f32x4 zero = {0.f, 0.f, 0.f, 0.f};
  f32x4 acc[4][4];
#pragma unroll
  for (int mi = 0; mi < 4; ++mi)
#pragma unroll
    for (int ni = 0; ni < 4; ++ni) acc[mi][ni] = zero;

  int nk = K >> 5;
  u16x8 ra0 = *(const u16x8*)(A + gA0);
  u16x8 ra1 = *(const u16x8*)(A + gA0 + (size_t)64 * K);
  u16x8 rb0 = *(const u16x8*)(Bw + gB0);
  u16x8 rb1 = *(const u16x8*)(Bw + gB0 + (size_t)64 * K);

  for (int kt = 0; kt < nk; ++kt) {
    __syncthreads();
    *(u16x8*)&As[ws0] = ra0; *(u16x8*)&As[ws1] = ra1;
    *(u16x8*)&Bs[ws0] = rb0; *(u16x8*)&Bs[ws1] = rb1;
    __syncthreads();
    if (kt + 1 < nk) {
      size_t kadd = (size_t)(kt + 1) * 32;
      ra0 = *(const u16x8*)(A + gA0 + kadd);
      ra1 = *(const u16x8*)(A + gA0 + (size_t)64 * K + kadd);
      rb0 = *(const u16x8*)(Bw + gB0 + kadd);
      rb1 = *(const u16x8*)(Bw + gB0 + (size_t)64 * K + kadd);
    }
    u16x8 af[4], bfr[4];
#pragma unroll
    for (int i = 0; i < 4; ++i) {
      af[i]  = *(const u16x8*)&As[aoff[i]];
      bfr[i] = *(const u16x8*)&Bs[boff[i]];
    }
#pragma unroll
    for (int mi = 0; mi < 4; ++mi)
#pragma unroll
      for (int ni = 0; ni < 4; ++ni)
        acc[mi][ni] = __builtin_amdgcn_mfma_f32_16x16x32_bf16(as_bf(af[mi]), as_bf(bfr[ni]),
                                                              acc[mi][ni], 0, 0, 0);
  }

#pragma unroll
  for (int mi = 0; mi < 4; ++mi) {
#pragma unroll
    for (int ni = 0; ni < 4; ++ni) {
      int col = bn * 128 + wn * 64 + ni * 16 + lr;
#pragma unroll
      for (int j = 0; j < 4; ++j) {
        int rowm = bm * 128 + wm * 64 + mi * 16 + 4 * lg + j;
        float v = acc[mi][ni][j];
        if constexpr (sizeof(OutT) == 2) C[(size_t)rowm * N + col] = f2bf(v);
        else                             C[(size_t)rowm * N + col] = v;
      }
    }
  }
}

// ---------------- Flash attention v2: swapped QK^T, 128-row q-tile, 4 waves ----------------
// q layout [m][HID]; k layout [m][HID]; vt layout [HID-feature rows][BS_TOT] (V^T from gemm).
// Block mapping: x&7 -> XCD partition (4 bh each), qt descending (longest first).
__global__ __launch_bounds__(256, 2) void attn_fwd(const unsigned short* __restrict__ qg,
                                                   const unsigned short* __restrict__ kg,
                                                   const unsigned short* __restrict__ vt,
                                                   unsigned short* __restrict__ ctx) {
  __shared__ __align__(16) unsigned short Ks[64 * 128];   // [kv][d] 16B-slot XOR swizzled
  __shared__ __align__(16) unsigned short Vs[128 * 64];   // [d][kv] 16B-slot XOR swizzled
  __shared__ __align__(16) unsigned short Ps[4 * 32 * 64]; // per-wave P, 8B-slot XOR swizzled

  int x = (int)blockIdx.x;            // 512 blocks
  int bh = (x & 7) * 4 + ((x >> 3) & 3);
  int qt = 15 - (x >> 5);
  int b = bh >> 4, h = bh & 15;
  int q0 = qt * 128;
  int nt = 2 * qt + 2;

  int tid = (int)threadIdx.x;
  int w = tid >> 6, l = tid & 63, lr = l & 15, lg = l >> 4;
  const float scale = 0.08838834764831845f;  // 1/sqrt(128)
  const int bS = b * S_LEN, h128 = h * HD;
  const int qw = q0 + w * 32;

  // ---- hoist Q fragments: 2 qf x 4 kk, lane lr = q-row within 16 ----
  u16x8 qfr[2][4];
#pragma unroll
  for (int qf = 0; qf < 2; ++qf) {
    const unsigned short* qb = qg + (size_t)(bS + qw + qf * 16 + lr) * HID + h128;
#pragma unroll
    for (int kk = 0; kk < 4; ++kk) qfr[qf][kk] = *(const u16x8*)(qb + kk * 32 + lg * 8);
  }

  f32x4 zero = {0.f, 0.f, 0.f, 0.f};
  f32x4 oacc[2][8];
#pragma unroll
  for (int qf = 0; qf < 2; ++qf)
#pragma unroll
    for (int nj = 0; nj < 8; ++nj) oacc[qf][nj] = zero;
  float mrow[2] = {-1e30f, -1e30f}, lsum[2] = {0.f, 0.f};

  // staging indices (4 chunks of 256 threads each)
  int rK[4], cK[4], dV[4], cV[4];
#pragma unroll
  for (int p = 0; p < 4; ++p) {
    int id = tid + p * 256;
    rK[p] = id >> 4; cK[p] = id & 15;
    dV[p] = id >> 3; cV[p] = id & 7;
  }

  u16x8 ka[4], va[4];
#pragma unroll
  for (int p = 0; p < 4; ++p) {
    ka[p] = *(const u16x8*)(kg + (size_t)(bS + rK[p]) * HID + h128 + cK[p] * 8);
    va[p] = *(const u16x8*)(vt + (size_t)(h128 + dV[p]) * BS_TOT + bS + cV[p] * 8);
  }

  for (int t = 0; t < nt; ++t) {
    int k0 = t * 64;
    __syncthreads();   // previous tile's LDS reads done
#pragma unroll
    for (int p = 0; p < 4; ++p) {
      *(u16x8*)&Ks[rK[p] * 128 + ((cK[p] ^ (rK[p] & 15)) * 8)] = ka[p];
      *(u16x8*)&Vs[dV[p] * 64 + ((cV[p] ^ (dV[p] & 7)) * 8)] = va[p];
    }
    __syncthreads();
    if (t + 1 < nt) {
      int k1 = k0 + 64;
#pragma unroll
      for (int p = 0; p < 4; ++p) {
        ka[p] = *(const u16x8*)(kg + (size_t)(bS + k1 + rK[p]) * HID + h128 + cK[p] * 8);
        va[p] = *(const u16x8*)(vt + (size_t)(h128 + dV[p]) * BS_TOT + bS + k1 + cV[p] * 8);
      }
    }

    if (k0 <= qw + 31) {   // wave has at least one unmasked row
      // ---- S^T = K Q^T : lane holds S[q=qf*16+lr][kv = ni*16+4lg+j] ----
      f32x4 sac[2][4];
#pragma unroll
      for (int qf = 0; qf < 2; ++qf)
#pragma unroll
        for (int ni = 0; ni < 4; ++ni) sac[qf][ni] = zero;
#pragma unroll
      for (int kk = 0; kk < 4; ++kk) {
#pragma unroll
        for (int ni = 0; ni < 4; ++ni) {
          u16x8 kf = *(const u16x8*)&Ks[(ni * 16 + lr) * 128 + (((kk * 4 + lg) ^ lr) * 8)];
          sac[0][ni] = __builtin_amdgcn_mfma_f32_16x16x32_bf16(as_bf(kf), as_bf(qfr[0][kk]), sac[0][ni], 0, 0, 0);
          sac[1][ni] = __builtin_amdgcn_mfma_f32_16x16x32_bf16(as_bf(kf), as_bf(qfr[1][kk]), sac[1][ni], 0, 0, 0);
        }
      }
      bool needmask = (k0 + 63 > qw);

#pragma unroll
      for (int qf = 0; qf < 2; ++qf) {
        float s[4][4];
#pragma unroll
        for (int ni = 0; ni < 4; ++ni)
#pragma unroll
          for (int j = 0; j < 4; ++j) s[ni][j] = sac[qf][ni][j] * scale;
        if (needmask) {
          int qgl = qw + qf * 16 + lr;
#pragma unroll
          for (int ni = 0; ni < 4; ++ni)
#pragma unroll
            for (int j = 0; j < 4; ++j)
              if (k0 + ni * 16 + 4 * lg + j > qgl) s[ni][j] = -1e30f;
        }
        float mx = s[0][0];
#pragma unroll
        for (int ni = 0; ni < 4; ++ni)
#pragma unroll
          for (int j = 0; j < 4; ++j) mx = fmaxf(mx, s[ni][j]);
        mx = fmaxf(mx, __shfl_xor(mx, 16));
        mx = fmaxf(mx, __shfl_xor(mx, 32));
        float mn = fmaxf(mrow[qf], mx);
        float al = __expf(mrow[qf] - mn);
        mrow[qf] = mn;
        float rs = 0.f;
#pragma unroll
        for (int ni = 0; ni < 4; ++ni)
#pragma unroll
          for (int j = 0; j < 4; ++j) { float p = __expf(s[ni][j] - mn); s[ni][j] = p; rs += p; }
        rs += __shfl_xor(rs, 16);
        rs += __shfl_xor(rs, 32);
        lsum[qf] = lsum[qf] * al + rs;
        // broadcast alpha to oacc row layout (row = 4lg+j)
        float a0 = __shfl(al, 4 * lg + 0, 16);
        float a1 = __shfl(al, 4 * lg + 1, 16);
        float a2 = __shfl(al, 4 * lg + 2, 16);
        float a3 = __shfl(al, 4 * lg + 3, 16);
#pragma unroll
        for (int nj = 0; nj < 8; ++nj) {
          oacc[qf][nj][0] *= a0; oacc[qf][nj][1] *= a1;
          oacc[qf][nj][2] *= a2; oacc[qf][nj][3] *= a3;
        }
        // pack P -> per-wave swizzled LDS (8B slots)
        unsigned short* pw = &Ps[w * 2048];
#pragma unroll
        for (int ni = 0; ni < 4; ++ni) {
          u16x4 pv = {f2bf(s[ni][0]), f2bf(s[ni][1]), f2bf(s[ni][2]), f2bf(s[ni][3])};
          *(u16x4*)&pw[(qf * 16 + lr) * 64 + (((2 * ni + (lg >> 1)) ^ (lr & 7)) * 8) + (lg & 1) * 4] = pv;
        }
      }

      // ---- O += P V : A = P frags, B = VT frags ----
      const unsigned short* pw = &Ps[w * 2048];
#pragma unroll
      for (int kk2 = 0; kk2 < 2; ++kk2) {
        u16x8 pa0 = *(const u16x8*)&pw[(0 * 16 + lr) * 64 + (((kk2 * 4 + lg) ^ (lr & 7)) * 8)];
        u16x8 pa1 = *(const u16x8*)&pw[(1 * 16 + lr) * 64 + (((kk2 * 4 + lg) ^ (lr & 7)) * 8)];
#pragma unroll
        for (int nj = 0; nj < 8; ++nj) {
          u16x8 vf = *(const u16x8*)&Vs[(nj * 16 + lr) * 64 + (((kk2 * 4 + lg) ^ (lr & 7)) * 8)];
          oacc[0][nj] = __builtin_amdgcn_mfma_f32_16x16x32_bf16(as_bf(pa0), as_bf(vf), oacc[0][nj], 0, 0, 0);
          oacc[1][nj] = __builtin_amdgcn_mfma_f32_16x16x32_bf16(as_bf(pa1), as_bf(vf), oacc[1][nj], 0, 0, 0);
        }
      }
    }
  }

  // ---- epilogue: ctx[q][h*128+d] = O / lsum ----
#pragma unroll
  for (int qf = 0; qf < 2; ++qf) {
    float rl = 1.0f / lsum[qf];
    float r0 = __shfl(rl, 4 * lg + 0, 16);
    float r1 = __shfl(rl, 4 * lg + 1, 16);
    float r2 = __shfl(rl, 4 * lg + 2, 16);
    float r3 = __shfl(rl, 4 * lg + 3, 16);
    size_t obase = (size_t)(bS + qw + qf * 16 + 4 * lg) * HID + h128;
#pragma unroll
    for (int nj = 0; nj < 8; ++nj) {
      ctx[obase + 0 * HID + nj * 16 + lr] = f2bf(oacc[qf][nj][0] * r0);
      ctx[obase + 1 * HID + nj * 16 + lr] = f2bf(oacc[qf][nj][1] * r1);
      ctx[obase + 2 * HID + nj * 16 + lr] = f2bf(oacc[qf][nj][2] * r2);
      ctx[obase + 3 * HID + nj * 16 + lr] = f2bf(oacc[qf][nj][3] * r3);
    }
  }
}

// ---------------- launch ----------------
extern "C" void kernel_launch(void* const* d_in, const int* in_sizes, int n_in,
                              void* d_out, int out_size, void* d_ws, size_t ws_size,
                              hipStream_t stream) {
  const float* hs = (const float*)d_in[0];
  const float* Wq = (const float*)d_in[1];
  const float* Wk = (const float*)d_in[2];
  const float* Wv = (const float*)d_in[3];
  const float* Wo = (const float*)d_in[4];

  char* ws = (char*)d_ws;
  unsigned short* hsb = (unsigned short*)(ws);                    // 16 MB (reused as ctx)
  unsigned short* wqb = (unsigned short*)(ws + 16777216);         // 8 MB
  unsigned short* wkb = (unsigned short*)(ws + 25165824);
  unsigned short* wvb = (unsigned short*)(ws + 33554432);
  unsigned short* wob = (unsigned short*)(ws + 41943040);
  unsigned short* qb  = (unsigned short*)(ws + 50331648);         // 16 MB
  unsigned short* kb  = (unsigned short*)(ws + 67108864);
  unsigned short* vtb = (unsigned short*)(ws + 83886080);         // V^T [2048][4096]
  float* ctab = (float*)(ws + 100663296);
  float* stab = (float*)(ws + 101187584);
  unsigned short* ctxb = hsb;  // overlay: hsb fully consumed before attn writes

  cvt_bf16<<<8192, 256, 0, stream>>>(hs, hsb);
  cvt_bf16<<<4096, 256, 0, stream>>>(Wq, wqb);
  cvt_bf16<<<4096, 256, 0, stream>>>(Wk, wkb);
  cvt_bf16<<<4096, 256, 0, stream>>>(Wv, wvb);
  cvt_bf16<<<4096, 256, 0, stream>>>(Wo, wob);
  rope_table<<<512, 256, 0, stream>>>(ctab, stab);

  gemm_bt<unsigned short><<<512, 256, 0, stream>>>(hsb, wqb, qb, BS_TOT, HID, HID);
  gemm_bt<unsigned short><<<512, 256, 0, stream>>>(hsb, wkb, kb, BS_TOT, HID, HID);
  // V^T directly: C[o][bs] = sum_h Wv[o][h] * hs[bs][h]
  gemm_bt<unsigned short><<<512, 256, 0, stream>>>(wvb, hsb, vtb, HID, BS_TOT, HID);

  rope_apply<<<16384, 256, 0, stream>>>(qb, kb, ctab, stab);

  attn_fwd<<<512, 256, 0, stream>>>(qb, kb, vtb, ctxb);

  gemm_bt<float><<<512, 256, 0, stream>>>(ctxb, wob, (float*)d_out, BS_TOT, HID, HID);

  (void)in_sizes; (void)n_in; (void)out_size; (void)ws_size;
}